// Round 7
// baseline (205.847 us; speedup 1.0000x reference)
//
#include <hip/hip_runtime.h>

#define DIM    256
#define HALF   128
#define F0     10
#define F1     25
#define B0     1024
#define M1     10240
#define NNODES 100000
#define NTILES 6250            // 16-row tiles
#define TPB    5               // tiles per xform block -> 1250 blocks

typedef __attribute__((ext_vector_type(8))) short bf16x8;  // 8 bf16 = 4 VGPRs
typedef __attribute__((ext_vector_type(4))) float f32x4;

#define LSTRIDE 264   // LDS row stride (elements)

__device__ __forceinline__ unsigned short f2bf(float x) {
    union { float f; unsigned u; } v; v.f = x;
    unsigned r = v.u + 0x7fffu + ((v.u >> 16) & 1u);   // RNE
    return (unsigned short)(r >> 16);
}
__device__ __forceinline__ float bf2f(unsigned b) {    // low 16 bits used
    union { unsigned u; float f; } v; v.u = b << 16;
    return v.f;
}
__device__ __forceinline__ unsigned packbf(float a, float b) {
    return (unsigned)f2bf(a) | ((unsigned)f2bf(b) << 16);
}

// ---------- Prep: W0_{self,neigh} -> bf16 B-fragments in frag-linear order.
// B-frag (tile t, kstep kk), lane = q*16+n, j=0..7 : W[kk*32+q*8+j][t*16+n]
__global__ __launch_bounds__(64) void prep_w(
    const float* __restrict__ Ws,
    const float* __restrict__ Wn,
    unsigned short* __restrict__ bfrag)
{
    const int bx   = blockIdx.x;       // [0,128)
    const int mat  = bx >> 6;
    const int f    = bx & 63;          // t*8+kk
    const int t    = f >> 3, kk = f & 7;
    const int lane = threadIdx.x;
    const int n    = lane & 15, q = lane >> 4;
    const float* W = mat ? Wn : Ws;

    __align__(16) unsigned short tmp[8];
    #pragma unroll
    for (int j = 0; j < 8; ++j)
        tmp[j] = f2bf(W[(kk * 32 + q * 8 + j) * HALF + t * 16 + n]);
    *(uint4*)(bfrag + ((size_t)(mat * 64 + f) * 64 + lane) * 8) = *(const uint4*)tmp;
}

// ---------- Xform: C_all[node] = [feat@W0s (cols 0:128) || feat@W0n (128:256)] bf16.
// 1250 blocks x 512 thr; 5 sequential 16-row tiles per block; B-frags in registers.
__global__ __launch_bounds__(512, 2) void sage_xform(
    const float* __restrict__ feat,
    const unsigned short* __restrict__ bfrag,
    unsigned short* __restrict__ C_all)
{
    __shared__ __align__(16) unsigned short sh[16][LSTRIDE];   // 8.4 KB

    const int tid  = threadIdx.x;
    const int wv   = __builtin_amdgcn_readfirstlane(tid >> 6); // 0..7
    const int lane = tid & 63;
    const int h    = wv >> 2;          // 0: W0s half, 1: W0n half
    const int t0   = (wv & 3) * 2;     // col tiles t0, t0+1 within half
    const int m    = lane & 15;
    const int q    = lane >> 4;

    // register-resident B fragments: 2 tiles x 8 ksteps x 4 VGPRs = 64 VGPRs
    bf16x8 Bf0[8], Bf1[8];
    #pragma unroll
    for (int kk = 0; kk < 8; ++kk) {
        Bf0[kk] = *(const bf16x8*)(bfrag + ((size_t)(h * 64 + (t0 + 0) * 8 + kk) * 64 + lane) * 8);
        Bf1[kk] = *(const bf16x8*)(bfrag + ((size_t)(h * 64 + (t0 + 1) * 8 + kk) * 64 + lane) * 8);
    }

    const int tile0 = blockIdx.x * TPB;

    for (int i = 0; i < TPB; ++i) {
        const int rowbase = (tile0 + i) * 16;
        // stage 16 rows x 256 fp32 -> bf16 LDS. 1024 float4-chunks over 512 thr.
        #pragma unroll
        for (int k = 0; k < 2; ++k) {
            const int idx = k * 512 + tid;
            const int r   = idx >> 6;
            const int c4  = (idx & 63) * 4;
            const float4 v = *(const float4*)(feat + (size_t)(rowbase + r) * DIM + c4);
            *(uint2*)(&sh[r][c4]) = make_uint2(packbf(v.x, v.y), packbf(v.z, v.w));
        }
        __syncthreads();

        f32x4 acc0 = {0.f, 0.f, 0.f, 0.f};
        f32x4 acc1 = {0.f, 0.f, 0.f, 0.f};
        #pragma unroll
        for (int kk = 0; kk < 8; ++kk) {
            const bf16x8 af = *(const bf16x8*)(&sh[m][kk * 32 + q * 8]);
            acc0 = __builtin_amdgcn_mfma_f32_16x16x32_bf16(af, Bf0[kk], acc0, 0, 0, 0);
            acc1 = __builtin_amdgcn_mfma_f32_16x16x32_bf16(af, Bf1[kk], acc1, 0, 0, 0);
        }

        // C/D layout: col = lane&15 (m), row = q*4 + reg  [verified R4-R6]
        #pragma unroll
        for (int reg = 0; reg < 4; ++reg) {
            const size_t row = (size_t)rowbase + q * 4 + reg;
            C_all[row * DIM + h * HALF + (t0 + 0) * 16 + m] = f2bf(acc0[reg]);
            C_all[row * DIM + h * HALF + (t0 + 1) * 16 + m] = f2bf(acc1[reg]);
        }
        __syncthreads();   // protect sh before next tile's staging
    }
}

// ---------- Fused gather + final: one block per output row.
// rows[t], t<10 : n1 row r*10+t = relu(C_S[sn1]) || relu(mean25 C_G[sn2..])
// rows[10]      : n0 row r      = relu(C_S[sn0]) || relu(mean10 C_G[sn1..])
// then out[r] = concat(rows[10] @ W1s, mean10(rows[0..9]) @ W1n)
__global__ __launch_bounds__(256, 4) void sage_gf(
    const unsigned short* __restrict__ C_all,
    const int* __restrict__ sn0,
    const int* __restrict__ sn1,
    const int* __restrict__ sn2,
    const float* __restrict__ W1s,
    const float* __restrict__ W1n,
    float* __restrict__ out)
{
    __shared__ float rows[11][LSTRIDE];   // 11.6 KB
    __shared__ float agg[DIM];

    const unsigned* C = (const unsigned*)C_all;   // 128 uints (2 bf16 each) per node
    const int tid  = threadIdx.x;
    const int r    = blockIdx.x;
    const int wv   = __builtin_amdgcn_readfirstlane(tid >> 6);
    const int lane = tid & 63;

    for (int t = wv; t < 11; t += 4) {
        if (t < 10) {
            const int row = r * F0 + t;
            const int si  = sn1[row];                          // wave-uniform scalar
            const unsigned su = C[(size_t)si * 128 + lane];
            const float s0 = fmaxf(bf2f(su & 0xffffu), 0.f);
            const float s1 = fmaxf(bf2f(su >> 16), 0.f);

            float a0 = 0.f, a1 = 0.f;
            #pragma unroll
            for (int j = 0; j < F1; ++j) {
                const int gi = sn2[row * F1 + j];              // wave-uniform scalar
                const unsigned g = C[(size_t)gi * 128 + 64 + lane];
                a0 += bf2f(g & 0xffffu);
                a1 += bf2f(g >> 16);
            }
            a0 = fmaxf(a0 * (1.0f / F1), 0.f);
            a1 = fmaxf(a1 * (1.0f / F1), 0.f);

            float2 sv; sv.x = s0; sv.y = s1;
            float2 av; av.x = a0; av.y = a1;
            *(float2*)(&rows[t][2 * lane])        = sv;        // cols 0..127
            *(float2*)(&rows[t][HALF + 2 * lane]) = av;        // cols 128..255
        } else {
            const int si = sn0[r];
            const unsigned su = C[(size_t)si * 128 + lane];
            const float s0 = fmaxf(bf2f(su & 0xffffu), 0.f);
            const float s1 = fmaxf(bf2f(su >> 16), 0.f);

            float a0 = 0.f, a1 = 0.f;
            #pragma unroll
            for (int j = 0; j < F0; ++j) {
                const int gi = sn1[r * F0 + j];
                const unsigned g = C[(size_t)gi * 128 + 64 + lane];
                a0 += bf2f(g & 0xffffu);
                a1 += bf2f(g >> 16);
            }
            a0 = fmaxf(a0 * (1.0f / F0), 0.f);
            a1 = fmaxf(a1 * (1.0f / F0), 0.f);

            float2 sv; sv.x = s0; sv.y = s1;
            float2 av; av.x = a0; av.y = a1;
            *(float2*)(&rows[10][2 * lane])        = sv;
            *(float2*)(&rows[10][HALF + 2 * lane]) = av;
        }
    }
    __syncthreads();

    // mean10 of n1 rows -> agg  (thread per column; 2 lanes/bank = free)
    {
        float s = 0.f;
        #pragma unroll
        for (int t = 0; t < 10; ++t) s += rows[t][tid];
        agg[tid] = s * (1.0f / F0);
    }
    __syncthreads();

    // GEMV: thread tid -> output col tid. Waves 0-1 use n0 (rows[10]), waves 2-3 use agg.
    const bool nh  = (tid >= HALF);
    const float* __restrict__ x = nh ? agg : &rows[10][0];
    const float* __restrict__ W = nh ? W1n : W1s;
    const int col = nh ? (tid - HALF) : tid;

    float acc = 0.f;
    #pragma unroll 8
    for (int d = 0; d < DIM; ++d)
        acc += x[d] * W[d * HALF + col];

    out[(size_t)r * DIM + tid] = acc;
}

extern "C" void kernel_launch(void* const* d_in, const int* in_sizes, int n_in,
                              void* d_out, int out_size, void* d_ws, size_t ws_size,
                              hipStream_t stream) {
    (void)in_sizes; (void)n_in; (void)out_size; (void)ws_size;
    const float* feat = (const float*)d_in[0];
    const int*   sn0  = (const int*)  d_in[1];
    const int*   sn1  = (const int*)  d_in[2];
    const int*   sn2  = (const int*)  d_in[3];
    const float* W0s  = (const float*)d_in[4];
    const float* W0n  = (const float*)d_in[5];
    const float* W1s  = (const float*)d_in[6];
    const float* W1n  = (const float*)d_in[7];
    float* out = (float*)d_out;

    // ws layout (16B-aligned):
    //   [0, 51.2 MB)   C_all bf16       100000*256*2 = 51,200,000
    //   [+, 128 KB)    W0 B-fragments   131,072
    unsigned short* C_all = (unsigned short*)d_ws;
    unsigned short* bfrag = (unsigned short*)((char*)d_ws + 51200000);

    prep_w    <<<128, 64, 0, stream>>>(W0s, W0n, bfrag);
    sage_xform<<<NTILES / TPB, 512, 0, stream>>>(feat, bfrag, C_all);
    sage_gf   <<<B0, 256, 0, stream>>>(C_all, sn0, sn1, sn2, W1s, W1n, out);
}